// Round 1
// 238.291 us; speedup vs baseline: 1.2403x; 1.2403x over previous
//
#include <hip/hip_runtime.h>
#include <hip/hip_bf16.h>
#include <math.h>

#define BB 16
#define TT 2048
#define VV 512

typedef __attribute__((ext_vector_type(8))) short short8;
typedef __attribute__((ext_vector_type(4))) float floatx4;

static __device__ inline ushort f2bf(float f) {
  __hip_bfloat16 h = __float2bfloat16(f);
  return *(ushort*)&h;
}

// async 16B global->LDS DMA. LDS dest = wave-uniform base + lane*16.
static __device__ __forceinline__ void cp16(const void* g, void* l) {
  __builtin_amdgcn_global_load_lds((const __attribute__((address_space(1))) void*)g,
                                   (__attribute__((address_space(3))) void*)l, 16, 0, 0);
}

// Static-balance tile mapping: dispatcher assigns blocks round-robin mod 256,
// so a CU's co-resident set = ids {c, c+256, c+512, c+768} = same (x, y, z&3),
// q = z>>2 in {0,1,2,3}. Choose t from {r, r+8, 7-r, 15-r} (r = y&3): every
// co-set's total K-work sums to 136 exactly.
static __device__ __forceinline__ void balance_map(int y, int z, int* t_t, int* b) {
  const int r = y & 3, q = z >> 2;
  int t = (q == 0) ? r : (q == 1) ? (r + 8) : (q == 2) ? (7 - r) : (15 - r);
  *t_t = t;
  *b = ((z & 3) << 2) | (y >> 2);
}

// ---------------- builders ----------------

__global__ __launch_bounds__(256) void k_transpose_wq(const float* __restrict__ Wq,
                                                      ushort* __restrict__ WqT) {
  int u = blockIdx.x;
  for (int v = threadIdx.x; v < VV; v += blockDim.x)
    WqT[u * VV + v] = f2bf(Wq[(size_t)v * VV + u]);
}

__global__ __launch_bounds__(256) void k_build_pe(const float* __restrict__ h,
                                                  ushort* __restrict__ PE) {
  int t = blockIdx.x;
  ushort* out = PE + (size_t)t * TT;
  for (int p = threadIdx.x; p < TT; p += blockDim.x)
    out[p] = (p <= t) ? f2bf(h[t - p]) : (ushort)0;
}

// M[b,u,p]   = WqT[u, idx[b,p]]   (gathered Q-correlations, zero FLOPs)
// VvT[b,j,s] = Wv[j, idx[b,s]]
__global__ __launch_bounds__(256) void k_build_mv(const int* __restrict__ idx,
                                                  const float* __restrict__ Wv,
                                                  const ushort* __restrict__ WqT,
                                                  ushort* __restrict__ M,
                                                  ushort* __restrict__ VvT) {
  int bv = blockIdx.x;
  int b = bv >> 9, v = bv & (VV - 1);
  __shared__ float wrow[VV];
  __shared__ ushort qrow[VV];
  for (int u = threadIdx.x; u < VV; u += blockDim.x) {
    wrow[u] = Wv[(size_t)v * VV + u];
    qrow[u] = WqT[(size_t)v * VV + u];
  }
  __syncthreads();
  const int* row = idx + b * TT;
  ushort* om = M + (size_t)bv * TT;
  ushort* ov = VvT + (size_t)bv * TT;
  for (int s4 = threadIdx.x * 4; s4 < TT; s4 += blockDim.x * 4) {
    int4 iv = *(const int4*)(row + s4);
    ushort4 m, w;
    m.x = qrow[iv.x];  w.x = f2bf(wrow[iv.x]);
    m.y = qrow[iv.y];  w.y = f2bf(wrow[iv.y]);
    m.z = qrow[iv.z];  w.z = f2bf(wrow[iv.z]);
    m.w = qrow[iv.w];  w.w = f2bf(wrow[iv.w]);
    *(ushort4*)(om + s4) = m;
    *(ushort4*)(ov + s4) = w;
  }
}

// ---------------- 128x128 MFMA GEMM core ----------

#define GEMM_PRELUDE()                                                         \
  __shared__ __attribute__((aligned(16))) short As[128 * 32];                  \
  __shared__ __attribute__((aligned(16))) short Bs[128 * 32];                  \
  const int tid = threadIdx.x;                                                 \
  const int lane = tid & 63;                                                   \
  const int wm = (tid >> 6) & 1, wn = tid >> 7;                                \
  const int quad = lane >> 4, ln = lane & 15;                                  \
  const int rr = tid >> 2;                                                     \
  const int cg = (((tid & 3) ^ (rr & 3)) << 3);                                \
  short* a_dst = &As[tid * 8];                                                 \
  short* b_dst = &Bs[tid * 8];                                                 \
  const short* ap[4];                                                          \
  const short* bp[4];                                                          \
  _Pragma("unroll") for (int i = 0; i < 4; i++)                                \
      ap[i] = &As[(wm * 64 + i * 16 + ln) * 32 + ((quad ^ (ln & 3)) << 3)];    \
  _Pragma("unroll") for (int j = 0; j < 4; j++)                                \
      bp[j] = &Bs[(wn * 64 + j * 16 + ln) * 32 + ((quad ^ (ln & 3)) << 3)];

#define GEMM_KSTEP(A0, A1, B0, B1, KOA, KOB)                                   \
  {                                                                            \
    cp16((A0) + (KOA), a_dst);                                                 \
    cp16((A1) + (KOA), a_dst + 2048);                                          \
    cp16((B0) + (KOB), b_dst);                                                 \
    cp16((B1) + (KOB), b_dst + 2048);                                          \
    __syncthreads();                                                           \
    short8 af[4], bfr[4];                                                      \
    _Pragma("unroll") for (int i = 0; i < 4; i++) af[i] = *(const short8*)ap[i]; \
    _Pragma("unroll") for (int j = 0; j < 4; j++) bfr[j] = *(const short8*)bp[j]; \
    _Pragma("unroll") for (int i = 0; i < 4; i++)                              \
        _Pragma("unroll") for (int j = 0; j < 4; j++)                          \
            acc[i][j] =                                                        \
                __builtin_amdgcn_mfma_f32_16x16x32_bf16(af[i], bfr[j], acc[i][j], 0, 0, 0); \
    __syncthreads();                                                           \
  }

#define GEMM_KLOOP(NK)                                                         \
  _Pragma("unroll 1") for (int kt = 0; kt < (NK); ++kt) {                      \
    const int ko = kt << 5;                                                    \
    GEMM_KSTEP(a_src0, a_src1, b_src0, b_src1, ko, ko)                         \
  }

#define ZERO_ACC()                                                             \
  _Pragma("unroll") for (int i = 0; i < 4; i++)                                \
      _Pragma("unroll") for (int j = 0; j < 4; j++)                            \
          acc[i][j] = (floatx4){0.f, 0.f, 0.f, 0.f};

// GT[b,u,s] = sum_p M[b,u,p] * PE[s,p]  (causal K-extent: p < 128*(s_t+1))
// rows = u (blockIdx.x, 4 tiles), cols = s (static-balanced with b)
__global__ __launch_bounds__(256) void k_gemm_gt(const ushort* __restrict__ M,
                                                 const ushort* __restrict__ PE,
                                                 ushort* __restrict__ GT) {
  int s_t, b;
  balance_map(blockIdx.y, blockIdx.z, &s_t, &b);
  const int u_t = blockIdx.x;
  const int u0 = u_t << 7, s0 = s_t << 7;
  const int nk = (s_t << 2) + 4;
  GEMM_PRELUDE();
  const ushort* a_src0 = M + ((size_t)((b << 9) + u0 + rr)) * TT + cg;
  const ushort* a_src1 = a_src0 + (size_t)64 * TT;
  const ushort* b_src0 = PE + (size_t)(s0 + rr) * TT + cg;
  const ushort* b_src1 = b_src0 + (size_t)64 * TT;
  floatx4 acc[4][4];
  ZERO_ACC();
  GEMM_KLOOP(nk);
#pragma unroll
  for (int i = 0; i < 4; i++)
#pragma unroll
    for (int j = 0; j < 4; j++) {
      const int rowb = u0 + wm * 64 + i * 16 + quad * 4;
      const int col = s0 + wn * 64 + j * 16 + ln;
#pragma unroll
      for (int r = 0; r < 4; r++)
        GT[((size_t)((b << 9) + rowb + r)) * TT + col] = f2bf(acc[i][j][r]);
    }
}

// Pre-masked diagonal a2 tiles: a2d[b][t_t][r][c] = (c<=r) ? GT[b, idx[b,t0+r], t0+c] : 0
__global__ __launch_bounds__(256) void k_diag(const int* __restrict__ idx,
                                              const ushort* __restrict__ GT,
                                              ushort* __restrict__ a2d) {
  const int t_t = blockIdx.x, b = blockIdx.y;
  const int t0 = t_t << 7;
  ushort* outt = a2d + (((size_t)(b << 4) + t_t) << 14);
  for (int e = threadIdx.x; e < 2048; e += 256) {
    const int r = e >> 4;          // row in tile, 0..127
    const int c8 = (e & 15) << 3;  // col chunk start
    const int u = idx[(b << 11) + t0 + r];
    const ushort* src = GT + ((size_t)((b << 9) + u)) * TT + t0 + c8;
    ushort4 lo = *(const ushort4*)(src);
    ushort4 hi = *(const ushort4*)(src + 4);
    ushort vals[8] = {lo.x, lo.y, lo.z, lo.w, hi.x, hi.y, hi.z, hi.w};
    ushort o[8];
#pragma unroll
    for (int k = 0; k < 8; ++k) o[k] = (c8 + k <= r) ? vals[k] : (ushort)0;
    *(ushort4*)(outt + r * 128 + c8) = *(ushort4*)&o[0];
    *(ushort4*)(outt + r * 128 + c8 + 4) = *(ushort4*)&o[4];
  }
}

// logits[b,t,j] = sum_{s<=t} GT[b, idx[b,t], s] * VvT[b,j,s]
// main loop: s-tiles fully below the diagonal (A = gathered GT rows, unmasked)
// tail: 4 k-iters from the pre-masked diagonal tile a2d
__global__ __launch_bounds__(256) void k_gemm2(const int* __restrict__ idx,
                                               const ushort* __restrict__ GT,
                                               const ushort* __restrict__ a2d,
                                               const ushort* __restrict__ VvT,
                                               float* __restrict__ out) {
  int t_t, b;
  balance_map(blockIdx.y, blockIdx.z, &t_t, &b);
  const int j_t = blockIdx.x;
  const int t0 = t_t << 7, j0 = j_t << 7;
  const int nk_main = t_t << 2;
  GEMM_PRELUDE();
  const int u0 = idx[(b << 11) + t0 + rr];
  const int u1 = idx[(b << 11) + t0 + rr + 64];
  const ushort* a_src0 = GT + ((size_t)(b << 9) + u0) * TT + cg;
  const ushort* a_src1 = GT + ((size_t)(b << 9) + u1) * TT + cg;
  const ushort* b_src0 = VvT + ((size_t)((b << 9) + j0 + rr)) * TT + cg;
  const ushort* b_src1 = b_src0 + (size_t)64 * TT;
  floatx4 acc[4][4];
  ZERO_ACC();
  GEMM_KLOOP(nk_main);
  // diagonal tile (pre-masked), B continues at K offset nk_main*32
  const ushort* ad0 = a2d + (((size_t)(b << 4) + t_t) << 14) + (size_t)rr * 128 + cg;
  const ushort* ad1 = ad0 + (size_t)64 * 128;
#pragma unroll 1
  for (int kt = 0; kt < 4; ++kt) {
    const int koA = kt << 5;
    const int koB = (nk_main + kt) << 5;
    GEMM_KSTEP(ad0, ad1, b_src0, b_src1, koA, koB)
  }
#pragma unroll
  for (int i = 0; i < 4; i++)
#pragma unroll
    for (int j = 0; j < 4; j++) {
      const int rowb = t0 + wm * 64 + i * 16 + quad * 4;
      const int col = j0 + wn * 64 + j * 16 + ln;
#pragma unroll
      for (int r = 0; r < 4; r++)
        out[((size_t)((b << 11) + rowb + r)) * VV + col] = acc[i][j][r];
    }
}

extern "C" void kernel_launch(void* const* d_in, const int* in_sizes, int n_in,
                              void* d_out, int out_size, void* d_ws, size_t ws_size,
                              hipStream_t stream) {
  const int* idx = (const int*)d_in[0];
  const float* pos_table = (const float*)d_in[1];
  const float* Wq = (const float*)d_in[2];
  const float* Wv = (const float*)d_in[3];
  float* out = (float*)d_out;

  char* ws = (char*)d_ws;
  // ws layout (bytes):
  //   WqT bf16 (V,V)        :         0 ..    524288
  //   PE  bf16 (T,T)        :    524288 ..   8912896
  //   M   bf16 (B,V,T)      :   8912896 ..  42467328
  //   VvT bf16 (B,V,T)      :  42467328 ..  76021760
  //   GT  bf16 (B,V,T)      :  76021760 .. 109576192
  //   a2d bf16 (B,16,128,128): 109576192 .. 117964800
  ushort* WqT = (ushort*)(ws);
  ushort* PE = (ushort*)(ws + 524288UL);
  ushort* M = (ushort*)(ws + 8912896UL);
  ushort* VvT = (ushort*)(ws + 42467328UL);
  ushort* GT = (ushort*)(ws + 76021760UL);
  ushort* a2d = (ushort*)(ws + 109576192UL);

  k_transpose_wq<<<dim3(VV), 256, 0, stream>>>(Wq, WqT);
  k_build_pe<<<dim3(TT), 256, 0, stream>>>(pos_table, PE);
  k_build_mv<<<dim3(BB * VV), 256, 0, stream>>>(idx, Wv, WqT, M, VvT);
  k_gemm_gt<<<dim3(4, 16, BB), 256, 0, stream>>>(M, PE, GT);
  k_diag<<<dim3(16, BB), 256, 0, stream>>>(idx, GT, a2d);
  k_gemm2<<<dim3(4, 16, BB), 256, 0, stream>>>(idx, GT, a2d, VvT, out);
}

// Round 2
// 225.588 us; speedup vs baseline: 1.3102x; 1.0563x over previous
//
#include <hip/hip_runtime.h>
#include <hip/hip_bf16.h>
#include <math.h>

#define BB 16
#define TT 2048
#define VV 512

typedef __attribute__((ext_vector_type(8))) short short8;
typedef __attribute__((ext_vector_type(4))) float floatx4;

static __device__ inline ushort f2bf(float f) {
  __hip_bfloat16 h = __float2bfloat16(f);
  return *(ushort*)&h;
}

// async 16B global->LDS DMA. LDS dest = wave-uniform base + lane*16.
static __device__ __forceinline__ void cp16(const void* g, void* l) {
  __builtin_amdgcn_global_load_lds((const __attribute__((address_space(1))) void*)g,
                                   (__attribute__((address_space(3))) void*)l, 16, 0, 0);
}

// Static-balance tile mapping: dispatcher assigns blocks round-robin mod 256,
// so a CU's co-resident set = ids {c, c+256, c+512, c+768} = same (x, y, z&3),
// q = z>>2 in {0,1,2,3}. Choose t from {r, r+8, 7-r, 15-r} (r = y&3): every
// co-set's total K-work sums to 136 exactly.
static __device__ __forceinline__ void balance_map(int y, int z, int* t_t, int* b) {
  const int r = y & 3, q = z >> 2;
  int t = (q == 0) ? r : (q == 1) ? (r + 8) : (q == 2) ? (7 - r) : (15 - r);
  *t_t = t;
  *b = ((z & 3) << 2) | (y >> 2);
}

// ---------------- builders ----------------

__global__ __launch_bounds__(256) void k_transpose_wq(const float* __restrict__ Wq,
                                                      ushort* __restrict__ WqT) {
  int u = blockIdx.x;
  for (int v = threadIdx.x; v < VV; v += blockDim.x)
    WqT[u * VV + v] = f2bf(Wq[(size_t)v * VV + u]);
}

__global__ __launch_bounds__(256) void k_build_pe(const float* __restrict__ h,
                                                  ushort* __restrict__ PE) {
  int t = blockIdx.x;
  ushort* out = PE + (size_t)t * TT;
  for (int p = threadIdx.x; p < TT; p += blockDim.x)
    out[p] = (p <= t) ? f2bf(h[t - p]) : (ushort)0;
}

// M[b,u,p]   = WqT[u, idx[b,p]]   (gathered Q-correlations, zero FLOPs)
// VvT[b,j,s] = Wv[j, idx[b,s]]
__global__ __launch_bounds__(256) void k_build_mv(const int* __restrict__ idx,
                                                  const float* __restrict__ Wv,
                                                  const ushort* __restrict__ WqT,
                                                  ushort* __restrict__ M,
                                                  ushort* __restrict__ VvT) {
  int bv = blockIdx.x;
  int b = bv >> 9, v = bv & (VV - 1);
  __shared__ float wrow[VV];
  __shared__ ushort qrow[VV];
  for (int u = threadIdx.x; u < VV; u += blockDim.x) {
    wrow[u] = Wv[(size_t)v * VV + u];
    qrow[u] = WqT[(size_t)v * VV + u];
  }
  __syncthreads();
  const int* row = idx + b * TT;
  ushort* om = M + (size_t)bv * TT;
  ushort* ov = VvT + (size_t)bv * TT;
  for (int s4 = threadIdx.x * 4; s4 < TT; s4 += blockDim.x * 4) {
    int4 iv = *(const int4*)(row + s4);
    ushort4 m, w;
    m.x = qrow[iv.x];  w.x = f2bf(wrow[iv.x]);
    m.y = qrow[iv.y];  w.y = f2bf(wrow[iv.y]);
    m.z = qrow[iv.z];  w.z = f2bf(wrow[iv.z]);
    m.w = qrow[iv.w];  w.w = f2bf(wrow[iv.w]);
    *(ushort4*)(om + s4) = m;
    *(ushort4*)(ov + s4) = w;
  }
}

// ---------------- 128x128 MFMA GEMM core (double-buffered LDS) ----------
// Per k-step: issue stage of tile k+1 into buf^1 BEFORE computing tile k from
// buf. One __syncthreads per step (its implicit vmcnt(0) drain lands the
// prefetch, which had the whole ds_read+MFMA phase to fly). Intra-block
// overlap -> robust to low co-resident-block counts (residency ~1.6/CU here).

#define GEMM_PRELUDE()                                                         \
  __shared__ __attribute__((aligned(16))) short As[2 * 128 * 32];              \
  __shared__ __attribute__((aligned(16))) short Bs[2 * 128 * 32];              \
  const int tid = threadIdx.x;                                                 \
  const int lane = tid & 63;                                                   \
  const int wm = (tid >> 6) & 1, wn = tid >> 7;                                \
  const int quad = lane >> 4, ln = lane & 15;                                  \
  const int rr = tid >> 2;                                                     \
  const int cg = (((tid & 3) ^ (rr & 3)) << 3);                                \
  short* a_dst = &As[tid * 8];                                                 \
  short* b_dst = &Bs[tid * 8];                                                 \
  const short* ap[4];                                                          \
  const short* bp[4];                                                          \
  _Pragma("unroll") for (int i = 0; i < 4; i++)                                \
      ap[i] = &As[(wm * 64 + i * 16 + ln) * 32 + ((quad ^ (ln & 3)) << 3)];    \
  _Pragma("unroll") for (int j = 0; j < 4; j++)                                \
      bp[j] = &Bs[(wn * 64 + j * 16 + ln) * 32 + ((quad ^ (ln & 3)) << 3)];

// stage one 128x32 A-tile + 128x32 B-tile into buffer c (pointers pre-offset)
#define GEMM_STAGE(c, PA0, PA1, PB0, PB1)                                      \
  {                                                                            \
    const int _o = (c) << 12; /* 4096 shorts = one buffer */                   \
    cp16((PA0), a_dst + _o);                                                   \
    cp16((PA1), a_dst + _o + 2048);                                            \
    cp16((PB0), b_dst + _o);                                                   \
    cp16((PB1), b_dst + _o + 2048);                                            \
  }

#define GEMM_COMPUTE(c)                                                        \
  {                                                                            \
    const int _o = (c) << 12;                                                  \
    short8 af[4], bfr[4];                                                      \
    _Pragma("unroll") for (int i = 0; i < 4; i++)                              \
        af[i] = *(const short8*)(ap[i] + _o);                                  \
    _Pragma("unroll") for (int j = 0; j < 4; j++)                              \
        bfr[j] = *(const short8*)(bp[j] + _o);                                 \
    _Pragma("unroll") for (int i = 0; i < 4; i++)                              \
        _Pragma("unroll") for (int j = 0; j < 4; j++)                          \
            acc[i][j] = __builtin_amdgcn_mfma_f32_16x16x32_bf16(               \
                af[i], bfr[j], acc[i][j], 0, 0, 0);                            \
  }

#define ZERO_ACC()                                                             \
  _Pragma("unroll") for (int i = 0; i < 4; i++)                                \
      _Pragma("unroll") for (int j = 0; j < 4; j++)                            \
          acc[i][j] = (floatx4){0.f, 0.f, 0.f, 0.f};

// GT[b,u,s] = sum_p M[b,u,p] * PE[s,p]  (causal K-extent: p < 128*(s_t+1))
// rows = u (blockIdx.x, 4 tiles), cols = s (static-balanced with b)
__global__ __launch_bounds__(256) void k_gemm_gt(const ushort* __restrict__ M,
                                                 const ushort* __restrict__ PE,
                                                 ushort* __restrict__ GT) {
  int s_t, b;
  balance_map(blockIdx.y, blockIdx.z, &s_t, &b);
  const int u_t = blockIdx.x;
  const int u0 = u_t << 7, s0 = s_t << 7;
  const int nk = (s_t << 2) + 4;
  GEMM_PRELUDE();
  const ushort* a_src0 = M + ((size_t)((b << 9) + u0 + rr)) * TT + cg;
  const ushort* a_src1 = a_src0 + (size_t)64 * TT;
  const ushort* b_src0 = PE + (size_t)(s0 + rr) * TT + cg;
  const ushort* b_src1 = b_src0 + (size_t)64 * TT;
  floatx4 acc[4][4];
  ZERO_ACC();
  GEMM_STAGE(0, a_src0, a_src1, b_src0, b_src1);
  __syncthreads();
  int cur = 0;
#pragma unroll 1
  for (int kt = 0; kt < nk; ++kt) {
    if (kt + 1 < nk) {
      const int ko = (kt + 1) << 5;
      GEMM_STAGE(cur ^ 1, a_src0 + ko, a_src1 + ko, b_src0 + ko, b_src1 + ko);
    }
    GEMM_COMPUTE(cur);
    __syncthreads();
    cur ^= 1;
  }
#pragma unroll
  for (int i = 0; i < 4; i++)
#pragma unroll
    for (int j = 0; j < 4; j++) {
      const int rowb = u0 + wm * 64 + i * 16 + quad * 4;
      const int col = s0 + wn * 64 + j * 16 + ln;
#pragma unroll
      for (int r = 0; r < 4; r++)
        GT[((size_t)((b << 9) + rowb + r)) * TT + col] = f2bf(acc[i][j][r]);
    }
}

// Pre-masked diagonal a2 tiles: a2d[b][t_t][r][c] = (c<=r) ? GT[b, idx[b,t0+r], t0+c] : 0
__global__ __launch_bounds__(256) void k_diag(const int* __restrict__ idx,
                                              const ushort* __restrict__ GT,
                                              ushort* __restrict__ a2d) {
  const int t_t = blockIdx.x, b = blockIdx.y;
  const int t0 = t_t << 7;
  ushort* outt = a2d + (((size_t)(b << 4) + t_t) << 14);
  for (int e = threadIdx.x; e < 2048; e += 256) {
    const int r = e >> 4;          // row in tile, 0..127
    const int c8 = (e & 15) << 3;  // col chunk start
    const int u = idx[(b << 11) + t0 + r];
    const ushort* src = GT + ((size_t)((b << 9) + u)) * TT + t0 + c8;
    ushort4 lo = *(const ushort4*)(src);
    ushort4 hi = *(const ushort4*)(src + 4);
    ushort vals[8] = {lo.x, lo.y, lo.z, lo.w, hi.x, hi.y, hi.z, hi.w};
    ushort o[8];
#pragma unroll
    for (int k = 0; k < 8; ++k) o[k] = (c8 + k <= r) ? vals[k] : (ushort)0;
    *(ushort4*)(outt + r * 128 + c8) = *(ushort4*)&o[0];
    *(ushort4*)(outt + r * 128 + c8 + 4) = *(ushort4*)&o[4];
  }
}

// logits[b,t,j] = sum_{s<=t} GT[b, idx[b,t], s] * VvT[b,j,s]
// K-loop unified: kt < nk_main -> gathered GT rows (unmasked, below diagonal);
// kt >= nk_main -> pre-masked diagonal tile a2d. B continues along s.
__global__ __launch_bounds__(256) void k_gemm2(const int* __restrict__ idx,
                                               const ushort* __restrict__ GT,
                                               const ushort* __restrict__ a2d,
                                               const ushort* __restrict__ VvT,
                                               float* __restrict__ out) {
  int t_t, b;
  balance_map(blockIdx.y, blockIdx.z, &t_t, &b);
  const int j_t = blockIdx.x;
  const int t0 = t_t << 7, j0 = j_t << 7;
  const int nk_main = t_t << 2;
  const int nk = nk_main + 4;
  GEMM_PRELUDE();
  const int u0 = idx[(b << 11) + t0 + rr];
  const int u1 = idx[(b << 11) + t0 + rr + 64];
  const ushort* a_src0 = GT + ((size_t)(b << 9) + u0) * TT + cg;
  const ushort* a_src1 = GT + ((size_t)(b << 9) + u1) * TT + cg;
  const ushort* b_src0 = VvT + ((size_t)((b << 9) + j0 + rr)) * TT + cg;
  const ushort* b_src1 = b_src0 + (size_t)64 * TT;
  const ushort* ad0 = a2d + (((size_t)(b << 4) + t_t) << 14) + (size_t)rr * 128 + cg;
  const ushort* ad1 = ad0 + (size_t)64 * 128;
#define A0_AT(kt) ((kt) < nk_main ? a_src0 + ((kt) << 5) : ad0 + (((kt) - nk_main) << 5))
#define A1_AT(kt) ((kt) < nk_main ? a_src1 + ((kt) << 5) : ad1 + (((kt) - nk_main) << 5))
  floatx4 acc[4][4];
  ZERO_ACC();
  GEMM_STAGE(0, A0_AT(0), A1_AT(0), b_src0, b_src1);
  __syncthreads();
  int cur = 0;
#pragma unroll 1
  for (int kt = 0; kt < nk; ++kt) {
    if (kt + 1 < nk) {
      const int ko = (kt + 1) << 5;
      GEMM_STAGE(cur ^ 1, A0_AT(kt + 1), A1_AT(kt + 1), b_src0 + ko, b_src1 + ko);
    }
    GEMM_COMPUTE(cur);
    __syncthreads();
    cur ^= 1;
  }
#undef A0_AT
#undef A1_AT
#pragma unroll
  for (int i = 0; i < 4; i++)
#pragma unroll
    for (int j = 0; j < 4; j++) {
      const int rowb = t0 + wm * 64 + i * 16 + quad * 4;
      const int col = j0 + wn * 64 + j * 16 + ln;
#pragma unroll
      for (int r = 0; r < 4; r++)
        out[((size_t)((b << 11) + rowb + r)) * VV + col] = acc[i][j][r];
    }
}

extern "C" void kernel_launch(void* const* d_in, const int* in_sizes, int n_in,
                              void* d_out, int out_size, void* d_ws, size_t ws_size,
                              hipStream_t stream) {
  const int* idx = (const int*)d_in[0];
  const float* pos_table = (const float*)d_in[1];
  const float* Wq = (const float*)d_in[2];
  const float* Wv = (const float*)d_in[3];
  float* out = (float*)d_out;

  char* ws = (char*)d_ws;
  // ws layout (bytes):
  //   WqT bf16 (V,V)        :         0 ..    524288
  //   PE  bf16 (T,T)        :    524288 ..   8912896
  //   M   bf16 (B,V,T)      :   8912896 ..  42467328
  //   VvT bf16 (B,V,T)      :  42467328 ..  76021760
  //   GT  bf16 (B,V,T)      :  76021760 .. 109576192
  //   a2d bf16 (B,16,128,128): 109576192 .. 117964800
  ushort* WqT = (ushort*)(ws);
  ushort* PE = (ushort*)(ws + 524288UL);
  ushort* M = (ushort*)(ws + 8912896UL);
  ushort* VvT = (ushort*)(ws + 42467328UL);
  ushort* GT = (ushort*)(ws + 76021760UL);
  ushort* a2d = (ushort*)(ws + 109576192UL);

  k_transpose_wq<<<dim3(VV), 256, 0, stream>>>(Wq, WqT);
  k_build_pe<<<dim3(TT), 256, 0, stream>>>(pos_table, PE);
  k_build_mv<<<dim3(BB * VV), 256, 0, stream>>>(idx, Wv, WqT, M, VvT);
  k_gemm_gt<<<dim3(4, 16, BB), 256, 0, stream>>>(M, PE, GT);
  k_diag<<<dim3(16, BB), 256, 0, stream>>>(idx, GT, a2d);
  k_gemm2<<<dim3(4, 16, BB), 256, 0, stream>>>(idx, GT, a2d, VvT, out);
}